// Round 14
// baseline (39.920 us; speedup 1.0000x reference)
//
#include <hip/hip_runtime.h>
#include <math.h>

// ---------------- problem constants ----------------
constexpr int B  = 2, C = 64, H = 128, W = 128;
constexpr int Cr = 16;
constexpr int K  = 7, KK = 49;
constexpr int HW  = H * W;
constexpr int CHW = C * HW;
constexpr int NPIX = B * HW;       // 32768
constexpr float EPS = 1e-5f;

// ---- fast-path ws layout (floats): partialG[256*32] | done(u32) | pad
constexpr int PG_F = 256 * 32;     // 8192
constexpr size_t WS_NEED = (size_t)(PG_F + 64) * 4;

typedef _Float16 half4v __attribute__((ext_vector_type(4)));

// ==================== FAST PATH: single fused kernel ====================
// grid 512 x 256 (XCD-swizzled, all co-resident: 50.9 KB LDS -> 3/CU ceiling, 2/CU used).
// In-kernel stats handoff: half-0 blocks publish 32-word partials via device-scope
// atomicExch + vmcnt(0) + done-counter; everyone polls, then NORMAL-loads partials
// (L2 invalidated at dispatch, lines never touched pre-poll -> fresh).
constexpr int TLH = 8, TLW = 16;
constexpr int HR = TLH + 6, HC = TLW + 6;    // 14 x 22 halo
constexpr int RPT6 = 24;                     // halves per row
constexpr int CSP6 = HR * RPT6;              // 336 halves per channel

__global__ __launch_bounds__(256) void k_fused(
    const float* __restrict__ X, const float* __restrict__ w_reduce,
    const float* __restrict__ b_reduce, const float* __restrict__ gamma,
    const float* __restrict__ beta, const float* __restrict__ w_span,
    const float* __restrict__ b_span, float* __restrict__ partialG,
    unsigned int* __restrict__ done, float* __restrict__ out)
{
    __shared__ _Float16 Xs[32 * CSP6];    // 21504 B
    __shared__ _Float16 kcS[KK * 128];    // 12544 B
    __shared__ float wspS[KK * Cr];       // 3136 B
    __shared__ float bspS[KK + 3];
    __shared__ float wrS[Cr * 64];        // 4096 B
    __shared__ float brd[Cr];
    __shared__ float xchS[128 * 16];      // 8192 B (r-exchange, then act broadcast)
    __shared__ float red[256];
    __shared__ float tmp2[2][32];
    __shared__ float scS[16], ofS[16];

    const int t   = threadIdx.x;
    const int raw = blockIdx.x;
    const int wg  = (raw & 7) * 64 + (raw >> 3);    // bijective XCD swizzle (512%8==0)
    const int tile = wg & 127;                      // 16 tile-rows x 8 tile-cols
    const int half = (wg >> 7) & 1;                 // 32-ch half
    const int b    = wg >> 8;
    const int th0 = (tile >> 3) * TLH;
    const int tw0 = (tile & 7) * TLW;

    const int px  = t & 127;                // tile pixel (8 rows x 16 cols)
    const int kh2 = t >> 7;                 // wave-pair id: r-channel half & kc k-half
    const int p1r = px >> 4, p1c = px & 15;
    const int gh0 = th0 + p1r, gw0 = tw0 + p1c;     // always in-bounds (centers)

    // ---- (a) center loads issued first: this thread's 32-channel half, f32 ----
    const float* xcen = X + (size_t)b * CHW + (size_t)(kh2 * 32) * HW
                          + (size_t)gh0 * W + gw0;
    float xa[16], xb2[16];
    #pragma unroll
    for (int i = 0; i < 16; ++i) xa[i] = xcen[i * HW];
    #pragma unroll
    for (int i = 0; i < 16; ++i) xb2[i] = xcen[(16 + i) * HW];

    // ---- (b) stage w_reduce / b_reduce ----
    #pragma unroll
    for (int i = 0; i < 4; ++i) wrS[t + i * 256] = w_reduce[t + i * 256];
    if (t < Cr) brd[t] = b_reduce[t];
    __syncthreads();                        // S1

    // ---- (c) r partial over this thread's 32 channels ----
    float pr[16];
    #pragma unroll
    for (int o = 0; o < 16; ++o) pr[o] = (kh2 == 0) ? brd[o] : 0.f;
    #pragma unroll
    for (int i = 0; i < 16; ++i) {
        const float xv = xa[i];
        #pragma unroll
        for (int o = 0; o < 16; ++o)
            pr[o] = fmaf(xv, wrS[o * 64 + kh2 * 32 + i], pr[o]);
    }
    #pragma unroll
    for (int i = 0; i < 16; ++i) {
        const float xv = xb2[i];
        #pragma unroll
        for (int o = 0; o < 16; ++o)
            pr[o] = fmaf(xv, wrS[o * 64 + kh2 * 32 + 16 + i], pr[o]);
    }
    if (kh2 == 1) {
        #pragma unroll
        for (int o = 0; o < 16; ++o) xchS[px * 16 + o] = pr[o];
    }
    __syncthreads();                        // S2
    float r[16];
    if (kh2 == 0) {
        #pragma unroll
        for (int o = 0; o < 16; ++o) r[o] = pr[o] + xchS[px * 16 + o];
    }

    // ---- (d) half-0 blocks: block-reduce + publish partials (device-scope) ----
    if (half == 0 && kh2 == 0) {            // waves 0,1 (branch wave-uniform)
        const int lane = t & 63, wv = t >> 6;
        #pragma unroll
        for (int o = 0; o < 16; ++o) {
            float s = r[o], q = r[o] * r[o];
            #pragma unroll
            for (int off = 32; off > 0; off >>= 1) {
                s += __shfl_down(s, off);
                q += __shfl_down(q, off);
            }
            if (lane == 0) { tmp2[wv][o] = s; tmp2[wv][16 + o] = q; }
        }
    }
    __syncthreads();                        // S3
    if (half == 0) {
        if (t < 32) {                       // wave 0 only
            const int slot = b * 128 + tile;
            atomicExch(&partialG[slot * 32 + t], tmp2[0][t] + tmp2[1][t]);
        }
        if (t < 64) {                       // wave 0: drain its atomics
            asm volatile("s_waitcnt vmcnt(0)" ::: "memory");
        }
        if (t == 0) atomicAdd(done, 1u);
    }

    // ---- (e) stage X halo (32 ch of `half`) as f16 + span weights ----
    {
        const int scol = t & 31;             // cols 0..21 valid
        const int sch  = t >> 5;             // 0..7
        const int gw   = tw0 + scol - 3;
        const bool wok = (unsigned)gw < (unsigned)W;
        const float* xg = X + (size_t)b * CHW + (size_t)(half * 32) * HW;
        #pragma unroll
        for (int cb = 0; cb < 4; ++cb) {
            const int c = cb * 8 + sch;
            const float* xc = xg + (size_t)c * HW;
            _Float16* xs = Xs + c * CSP6 + scol;
            #pragma unroll
            for (int rr = 0; rr < HR; ++rr) {
                const int gh = th0 + rr - 3;
                float v = 0.f;
                if (wok && (unsigned)gh < (unsigned)H) v = xc[gh * W + gw];
                if (scol < HC) xs[rr * RPT6] = (_Float16)v;
            }
        }
    }
    if (t < 196) *(float4*)&wspS[t * 4] = *(const float4*)&w_span[t * 4];
    if (t >= 196 && t < 196 + KK) bspS[t - 196] = b_span[t - 196];

    // ---- (f) wait for all 256 partials ----
    if (t == 0) {
        while (atomicAdd(done, 0u) < 256u) __builtin_amdgcn_s_sleep(8);
    }
    __syncthreads();                        // S4

    // ---- (g) per-block stats reduce (256 slots, fixed order -> deterministic) ----
    {
        const int o = t & 31, seg = t >> 5;
        float acc = 0.f;
        #pragma unroll 8
        for (int j = 0; j < 32; ++j)
            acc += partialG[(size_t)(seg * 32 + j) * 32 + o];
        red[seg * 32 + o] = acc;
    }
    __syncthreads();                        // S5
    if (t < 64) {
        const int o2 = t & 31;
        float tot = 0.f;
        #pragma unroll
        for (int g = 0; g < 8; ++g) tot += red[g * 32 + o2];
        const float sq = __shfl(tot, (t & 31) + 16);
        if (t < 16) {
            const float mean = tot / (float)NPIX;
            const float var  = sq / (float)NPIX - mean * mean;
            const float sc   = gamma[t] * rsqrtf(var + EPS);
            scS[t] = sc;
            ofS[t] = beta[t] - mean * sc;
        }
    }
    __syncthreads();                        // S6

    // ---- (h) act broadcast + kc -> f16 LDS ----
    if (kh2 == 0) {
        #pragma unroll
        for (int o = 0; o < 16; ++o)
            xchS[px * 16 + o] = fmaxf(fmaf(scS[o], r[o], ofS[o]), 0.f);
    }
    __syncthreads();                        // S7
    {
        float act[16];
        #pragma unroll
        for (int o = 0; o < 16; ++o) act[o] = xchS[px * 16 + o];
        #pragma unroll
        for (int j = 0; j < 25; ++j) {
            const int k = kh2 * 25 + j;
            if (k < KK) {
                const float4 w0 = *(const float4*)&wspS[k * 16 + 0];
                const float4 w1 = *(const float4*)&wspS[k * 16 + 4];
                const float4 w2 = *(const float4*)&wspS[k * 16 + 8];
                const float4 w3 = *(const float4*)&wspS[k * 16 + 12];
                float v = bspS[k];
                v = fmaf(act[0],  w0.x, v); v = fmaf(act[1],  w0.y, v);
                v = fmaf(act[2],  w0.z, v); v = fmaf(act[3],  w0.w, v);
                v = fmaf(act[4],  w1.x, v); v = fmaf(act[5],  w1.y, v);
                v = fmaf(act[6],  w1.z, v); v = fmaf(act[7],  w1.w, v);
                v = fmaf(act[8],  w2.x, v); v = fmaf(act[9],  w2.y, v);
                v = fmaf(act[10], w2.z, v); v = fmaf(act[11], w2.w, v);
                v = fmaf(act[12], w3.x, v); v = fmaf(act[13], w3.y, v);
                v = fmaf(act[14], w3.z, v); v = fmaf(act[15], w3.w, v);
                kcS[k * 128 + px] = (_Float16)v;
            }
        }
    }
    __syncthreads();                        // S8: kcS + Xs ready

    // ---- (i) involution: thread = 4px strip x 4 channels (champion ph3) ----
    const int strip = t & 31;
    const int chg   = t >> 5;
    const int pr3 = strip >> 2, pc = (strip & 3) * 4;
    const int c0  = chg * 4;

    float acc[4][4];
    #pragma unroll
    for (int i = 0; i < 4; ++i)
        #pragma unroll
        for (int j = 0; j < 4; ++j) acc[i][j] = 0.f;

    #pragma unroll
    for (int kh = 0; kh < 7; ++kh) {
        half4v kcr[7];
        #pragma unroll
        for (int kw = 0; kw < 7; ++kw)
            kcr[kw] = *(const half4v*)&kcS[(kh * 7 + kw) * 128 + pr3 * 16 + pc];
        #pragma unroll
        for (int i = 0; i < 4; ++i) {
            const _Float16* xr = &Xs[(c0 + i) * CSP6 + (pr3 + kh) * RPT6 + pc];
            const half4v va = *(const half4v*)&xr[0];
            const half4v vb = *(const half4v*)&xr[4];
            const half4v vc = *(const half4v*)&xr[8];
            const _Float16 xw[12] = {va[0], va[1], va[2], va[3],
                                     vb[0], vb[1], vb[2], vb[3],
                                     vc[0], vc[1], vc[2], vc[3]};
            #pragma unroll
            for (int kw = 0; kw < 7; ++kw)
                #pragma unroll
                for (int j = 0; j < 4; ++j)
                    acc[i][j] = fmaf((float)kcr[kw][j], (float)xw[kw + j], acc[i][j]);
        }
    }

    float* ob = out + (size_t)b * CHW + (size_t)(half * 32 + c0) * HW
                    + (size_t)(th0 + pr3) * W + (tw0 + pc);
    #pragma unroll
    for (int i = 0; i < 4; ++i)
        *(float4*)&ob[(size_t)i * HW] = make_float4(acc[i][0], acc[i][1], acc[i][2], acc[i][3]);
}

// ==================== FALLBACK PATH (round-1, passing) ====================

constexpr int XS_F  = C * 196;
constexpr int KC_F  = KK * 64;
constexpr int ACT_F = Cr * 64;
constexpr int WR_F  = Cr * C;
constexpr int WSP_F = KK * Cr;
constexpr int SMEM_F = XS_F + KC_F + ACT_F + WR_F + WSP_F + KK + Cr + Cr;
constexpr int SMEM_BYTES = SMEM_F * 4;

__global__ __launch_bounds__(128) void k_reduce_stats(
    const float* __restrict__ X, const float* __restrict__ w_reduce,
    const float* __restrict__ b_reduce, float* __restrict__ partial)
{
    __shared__ float wr[WR_F];
    __shared__ float brd[Cr];
    __shared__ float tmp[2][32];
    const int t = threadIdx.x;
    for (int i = t; i < WR_F; i += 128) wr[i] = w_reduce[i];
    if (t < Cr) brd[t] = b_reduce[t];
    __syncthreads();
    const int p  = blockIdx.x * 128 + t;
    const int b  = p >> 14;
    const int hw = p & (HW - 1);
    const float* xb = X + b * CHW + hw;
    float r[Cr];
    #pragma unroll
    for (int o = 0; o < Cr; ++o) r[o] = brd[o];
    #pragma unroll 4
    for (int c = 0; c < C; ++c) {
        const float x = xb[c * HW];
        #pragma unroll
        for (int o = 0; o < Cr; ++o) r[o] = fmaf(x, wr[o * C + c], r[o]);
    }
    const int lane = t & 63, wv = t >> 6;
    #pragma unroll
    for (int o = 0; o < Cr; ++o) {
        float s = r[o], q = r[o] * r[o];
        #pragma unroll
        for (int off = 32; off > 0; off >>= 1) {
            s += __shfl_down(s, off);
            q += __shfl_down(q, off);
        }
        if (lane == 0) { tmp[wv][o] = s; tmp[wv][Cr + o] = q; }
    }
    __syncthreads();
    if (t < 32) partial[blockIdx.x * 32 + t] = tmp[0][t] + tmp[1][t];
}

__global__ __launch_bounds__(256) void k_stats_final(
    const float* __restrict__ partial, float* __restrict__ stats)
{
    __shared__ float red[256];
    __shared__ float fin[32];
    const int t = threadIdx.x;
    const int o = t & 31, g = t >> 5;
    float acc = 0.f;
    #pragma unroll 8
    for (int j = 0; j < 32; ++j) acc += partial[(g * 32 + j) * 32 + o];
    red[t] = acc;
    __syncthreads();
    if (t < 32) {
        float v = 0.f;
        #pragma unroll
        for (int g2 = 0; g2 < 8; ++g2) v += red[g2 * 32 + t];
        fin[t] = v;
    }
    __syncthreads();
    if (t < Cr) {
        const float mean = fin[t] / (float)NPIX;
        const float var  = fin[Cr + t] / (float)NPIX - mean * mean;
        stats[t]      = mean;
        stats[Cr + t] = rsqrtf(var + EPS);
    }
}

__global__ __launch_bounds__(256) void k_involution(
    const float* __restrict__ X, const float* __restrict__ w_reduce,
    const float* __restrict__ b_reduce, const float* __restrict__ gamma,
    const float* __restrict__ beta, const float* __restrict__ w_span,
    const float* __restrict__ b_span, const float* __restrict__ stats,
    float* __restrict__ out)
{
    extern __shared__ float smem[];
    float* Xs   = smem;
    float* kcS  = Xs  + XS_F;
    float* actS = kcS + KC_F;
    float* wrS  = actS + ACT_F;
    float* wspS = wrS + WR_F;
    float* bspS = wspS + WSP_F;
    float* scS  = bspS + KK;
    float* ofS  = scS + Cr;
    const int t    = threadIdx.x;
    const int bx   = blockIdx.x;
    const int b    = bx >> 8;
    const int tile = bx & 255;
    const int h0   = (tile >> 4) << 3;
    const int w0   = (tile & 15) << 3;
    const float* xbg = X + b * CHW;
    for (int idx = t; idx < XS_F; idx += 256) {
        const int c   = idx / 196;
        const int rem = idx - c * 196;
        const int r   = rem / 14;
        const int col = rem - r * 14;
        const int gh  = h0 + r - 3, gw = w0 + col - 3;
        float v = 0.f;
        if ((unsigned)gh < (unsigned)H && (unsigned)gw < (unsigned)W)
            v = xbg[c * HW + gh * W + gw];
        Xs[idx] = v;
    }
    for (int i = t; i < WR_F;  i += 256) wrS[i]  = w_reduce[i];
    for (int i = t; i < WSP_F; i += 256) wspS[i] = w_span[i];
    if (t < KK) bspS[t] = b_span[t];
    if (t < Cr) {
        const float m  = stats[t];
        const float rs = stats[Cr + t];
        const float gm = gamma[t];
        scS[t] = gm * rs;
        ofS[t] = (b_reduce[t] - m) * gm * rs + beta[t];
    }
    __syncthreads();
    const int pix = t & 63;
    const int grp = t >> 6;
    const int ph  = pix >> 3, pw = pix & 7;
    {
        const int base = (ph + 3) * 14 + (pw + 3);
        float d0 = 0.f, d1 = 0.f, d2 = 0.f, d3 = 0.f;
        #pragma unroll 8
        for (int c = 0; c < C; ++c) {
            const float x = Xs[c * 196 + base];
            d0 = fmaf(x, wrS[(grp * 4 + 0) * C + c], d0);
            d1 = fmaf(x, wrS[(grp * 4 + 1) * C + c], d1);
            d2 = fmaf(x, wrS[(grp * 4 + 2) * C + c], d2);
            d3 = fmaf(x, wrS[(grp * 4 + 3) * C + c], d3);
        }
        const float d[4] = {d0, d1, d2, d3};
        #pragma unroll
        for (int j = 0; j < 4; ++j) {
            const int o = grp * 4 + j;
            actS[o * 64 + pix] = fmaxf(fmaf(scS[o], d[j], ofS[o]), 0.f);
        }
    }
    __syncthreads();
    for (int k = grp; k < KK; k += 4) {
        float v = bspS[k];
        #pragma unroll
        for (int o = 0; o < Cr; ++o)
            v = fmaf(actS[o * 64 + pix], wspS[k * Cr + o], v);
        kcS[k * 64 + pix] = v;
    }
    __syncthreads();
    float acc[16];
    #pragma unroll
    for (int i = 0; i < 16; ++i) acc[i] = 0.f;
    const float* xsc = Xs + grp * 16 * 196;
    #pragma unroll
    for (int k = 0; k < KK; ++k) {
        const int kh = k / 7, kw = k - (k / 7) * 7;
        const float kcv = kcS[k * 64 + pix];
        const int xoff = (ph + kh) * 14 + (pw + kw);
        #pragma unroll
        for (int i = 0; i < 16; ++i)
            acc[i] = fmaf(kcv, xsc[i * 196 + xoff], acc[i]);
    }
    float* ob = out + b * CHW + (grp * 16) * HW + (h0 + ph) * W + (w0 + pw);
    #pragma unroll
    for (int i = 0; i < 16; ++i) ob[i * HW] = acc[i];
}

// ==================== launch ====================

extern "C" void kernel_launch(void* const* d_in, const int* in_sizes, int n_in,
                              void* d_out, int out_size, void* d_ws, size_t ws_size,
                              hipStream_t stream) {
    const float* X        = (const float*)d_in[0];
    const float* w_reduce = (const float*)d_in[1];
    const float* b_reduce = (const float*)d_in[2];
    const float* gamma    = (const float*)d_in[3];
    const float* beta     = (const float*)d_in[4];
    const float* w_span   = (const float*)d_in[5];
    const float* b_span   = (const float*)d_in[6];
    float* out = (float*)d_out;
    float* ws  = (float*)d_ws;

    if (ws_size >= WS_NEED) {
        float* partialG = ws;
        unsigned int* done = (unsigned int*)(ws + PG_F);
        hipMemsetAsync(done, 0, sizeof(unsigned int), stream);
        k_fused<<<512, 256, 0, stream>>>(X, w_reduce, b_reduce, gamma, beta,
                                         w_span, b_span, partialG, done, out);
    } else {
        float* partial = ws;
        float* stats   = ws + 8192;
        hipFuncSetAttribute((const void*)k_involution,
                            hipFuncAttributeMaxDynamicSharedMemorySize, SMEM_BYTES);
        k_reduce_stats<<<256, 128, 0, stream>>>(X, w_reduce, b_reduce, partial);
        k_stats_final<<<1, 256, 0, stream>>>(partial, stats);
        k_involution<<<512, 256, SMEM_BYTES, stream>>>(
            X, w_reduce, b_reduce, gamma, beta, w_span, b_span, stats, out);
    }
}

// Round 15
// 28.908 us; speedup vs baseline: 1.3809x; 1.3809x over previous
//
#include <hip/hip_runtime.h>
#include <math.h>

// ---------------- problem constants ----------------
constexpr int B  = 2, C = 64, H = 128, W = 128;
constexpr int Cr = 16;
constexpr int K  = 7, KK = 49;
constexpr int HW  = H * W;
constexpr int CHW = C * HW;
constexpr int NPIX = B * HW;       // 32768
constexpr float EPS = 1e-5f;

// ---- fast-path ws layout (floats): r[NPIX][16] | partial[512*32]
constexpr int R_F = NPIX * Cr;     // 524288
constexpr int P_F = 512 * 32;      // 16384
constexpr size_t WS_NEED = (size_t)(R_F + P_F + 64) * 4;

typedef _Float16 half4v __attribute__((ext_vector_type(4)));

// ==================== FAST PATH (champion, 28.9-29.2 us measured) ====================

// A: r = X . w_reduce + b_reduce (+ per-block stats partials). 512 x 256,
// 4 threads/pixel + LDS exchange -> 8 waves/CU.
__global__ __launch_bounds__(256) void k_reduce_r(
    const float* __restrict__ X, const float* __restrict__ w_reduce,
    const float* __restrict__ b_reduce, float* __restrict__ r_ws,
    float* __restrict__ partial)
{
    __shared__ float wrS[Cr * C];
    __shared__ float tmpA[4][Cr][64];
    const int t = threadIdx.x;
    for (int i = t; i < Cr * C; i += 256) wrS[i] = w_reduce[i];
    __syncthreads();

    const int pixl = t & 63, cg = t >> 6;
    const int p = blockIdx.x * 64 + pixl;
    const int b = p >> 14, hw = p & (HW - 1);
    const float* xb = X + (size_t)b * CHW + hw;

    float x[16];
    #pragma unroll
    for (int i = 0; i < 16; ++i) x[i] = xb[(cg * 16 + i) * HW];

    float rp[16];
    #pragma unroll
    for (int o = 0; o < 16; ++o) rp[o] = (cg == 0) ? b_reduce[o] : 0.f;
    #pragma unroll
    for (int i = 0; i < 16; ++i) {
        const float xv = x[i];
        #pragma unroll
        for (int o = 0; o < 16; ++o)
            rp[o] = fmaf(xv, wrS[o * 64 + cg * 16 + i], rp[o]);
    }
    #pragma unroll
    for (int o = 0; o < 16; ++o) tmpA[cg][o][pixl] = rp[o];
    __syncthreads();

    float rr[4];
    #pragma unroll
    for (int j = 0; j < 4; ++j) {
        const int o = cg * 4 + j;
        rr[j] = tmpA[0][o][pixl] + tmpA[1][o][pixl] + tmpA[2][o][pixl] + tmpA[3][o][pixl];
    }
    *(float4*)&r_ws[(size_t)p * 16 + cg * 4] = make_float4(rr[0], rr[1], rr[2], rr[3]);

    float s[4], q[4];
    #pragma unroll
    for (int j = 0; j < 4; ++j) { s[j] = rr[j]; q[j] = rr[j] * rr[j]; }
    #pragma unroll
    for (int off = 32; off > 0; off >>= 1) {
        #pragma unroll
        for (int j = 0; j < 4; ++j) {
            s[j] += __shfl_down(s[j], off);
            q[j] += __shfl_down(q[j], off);
        }
    }
    if ((t & 63) == 0) {
        #pragma unroll
        for (int j = 0; j < 4; ++j) {
            partial[blockIdx.x * 32 + cg * 4 + j]      = s[j];
            partial[blockIdx.x * 32 + 16 + cg * 4 + j] = q[j];
        }
    }
}

// C: fused redundant-stats + act/kc + involution. 32 ch/block, 16w x 8h tile,
// grid 512 XCD-swizzled, f16 LDS (38.6 KB). Measured champion.
constexpr int TLH = 8, TLW = 16;
constexpr int HR = TLH + 6, HC = TLW + 6;    // 14 x 22 halo
constexpr int RPT6 = 24;                     // halves per row
constexpr int CSP6 = HR * RPT6;              // 336 halves per channel

__global__ __launch_bounds__(256) void k_inv6(
    const float* __restrict__ X, const float* __restrict__ r_ws,
    const float* __restrict__ partial, const float* __restrict__ gamma,
    const float* __restrict__ beta, const float* __restrict__ w_span,
    const float* __restrict__ b_span, float* __restrict__ out)
{
    __shared__ _Float16 Xs[32 * CSP6];    // 21504 B
    __shared__ _Float16 kcS[KK * 128];    // 12544 B
    __shared__ float wspS[KK * Cr];       // 3136 B
    __shared__ float bspS[KK + 3];
    __shared__ float red[256];
    __shared__ float scS[16], ofS[16];

    const int t   = threadIdx.x;
    const int raw = blockIdx.x;
    const int wg  = (raw & 7) * 64 + (raw >> 3);    // bijective XCD swizzle (512%8==0)
    const int tile = wg & 127;                      // 16 tile-rows x 8 tile-cols
    const int half = (wg >> 7) & 1;                 // 32-ch half
    const int b    = wg >> 8;
    const int th0 = (tile >> 3) * TLH;
    const int tw0 = (tile & 7) * TLW;

    // ---- r loads issued early ----
    const int px = t & 127;                 // tile pixel (8 rows x 16 cols)
    const int kh2 = t >> 7;                 // k-range half
    const int p1r = px >> 4, p1c = px & 15;
    const size_t gp = (size_t)b * HW + (size_t)(th0 + p1r) * W + (tw0 + p1c);
    const float4 r0 = *(const float4*)&r_ws[gp * 16 + 0];
    const float4 r1 = *(const float4*)&r_ws[gp * 16 + 4];
    const float4 r2 = *(const float4*)&r_ws[gp * 16 + 8];
    const float4 r3 = *(const float4*)&r_ws[gp * 16 + 12];

    // ---- stage X halo (this block's 32 channels) as f16 ----
    {
        const int scol = t & 31;             // cols 0..21 valid
        const int sch  = t >> 5;             // 0..7
        const int gw   = tw0 + scol - 3;
        const bool wok = (unsigned)gw < (unsigned)W;
        const float* xg = X + (size_t)b * CHW + (size_t)(half * 32) * HW;
        #pragma unroll
        for (int cb = 0; cb < 4; ++cb) {
            const int c = cb * 8 + sch;
            const float* xc = xg + (size_t)c * HW;
            _Float16* xs = Xs + c * CSP6 + scol;
            #pragma unroll
            for (int r = 0; r < HR; ++r) {
                const int gh = th0 + r - 3;
                float v = 0.f;
                if (wok && (unsigned)gh < (unsigned)H) v = xc[gh * W + gw];
                if (scol < HC) xs[r * RPT6] = (_Float16)v;
            }
        }
    }

    // ---- stage w_span/b_span ----
    if (t < 196) *(float4*)&wspS[t * 4] = *(const float4*)&w_span[t * 4];
    if (t >= 196 && t < 196 + KK) bspS[t - 196] = b_span[t - 196];

    // ---- redundant per-block stats reduce (fixed order -> deterministic) ----
    {
        const int o = t & 31, seg = t >> 5;
        float acc = 0.f;
        #pragma unroll 16
        for (int j = 0; j < 64; ++j) acc += partial[(size_t)(seg * 64 + j) * 32 + o];
        red[seg * 32 + o] = acc;
    }
    __syncthreads();                         // sync1
    if (t < 64) {
        const int o2 = t & 31;
        float tot = 0.f;
        #pragma unroll
        for (int g = 0; g < 8; ++g) tot += red[g * 32 + o2];
        const float sq = __shfl(tot, (t & 31) + 16);
        if (t < 16) {
            const float mean = tot / (float)NPIX;
            const float var  = sq / (float)NPIX - mean * mean;
            const float sc   = gamma[t] * rsqrtf(var + EPS);
            scS[t] = sc;
            ofS[t] = beta[t] - mean * sc;
        }
    }
    __syncthreads();                         // sync2: sc/of + wspS ready

    // ---- act (regs) + kc -> f16 LDS ----
    {
        float act[16];
        const float rv[16] = {r0.x, r0.y, r0.z, r0.w, r1.x, r1.y, r1.z, r1.w,
                              r2.x, r2.y, r2.z, r2.w, r3.x, r3.y, r3.z, r3.w};
        #pragma unroll
        for (int o = 0; o < 16; ++o)
            act[o] = fmaxf(fmaf(scS[o], rv[o], ofS[o]), 0.f);
        #pragma unroll
        for (int j = 0; j < 25; ++j) {
            const int k = kh2 * 25 + j;
            if (k < KK) {
                const float4 w0 = *(const float4*)&wspS[k * 16 + 0];
                const float4 w1 = *(const float4*)&wspS[k * 16 + 4];
                const float4 w2 = *(const float4*)&wspS[k * 16 + 8];
                const float4 w3 = *(const float4*)&wspS[k * 16 + 12];
                float v = bspS[k];
                v = fmaf(act[0],  w0.x, v); v = fmaf(act[1],  w0.y, v);
                v = fmaf(act[2],  w0.z, v); v = fmaf(act[3],  w0.w, v);
                v = fmaf(act[4],  w1.x, v); v = fmaf(act[5],  w1.y, v);
                v = fmaf(act[6],  w1.z, v); v = fmaf(act[7],  w1.w, v);
                v = fmaf(act[8],  w2.x, v); v = fmaf(act[9],  w2.y, v);
                v = fmaf(act[10], w2.z, v); v = fmaf(act[11], w2.w, v);
                v = fmaf(act[12], w3.x, v); v = fmaf(act[13], w3.y, v);
                v = fmaf(act[14], w3.z, v); v = fmaf(act[15], w3.w, v);
                kcS[k * 128 + px] = (_Float16)v;
            }
        }
    }
    __syncthreads();                         // sync3: kcS + Xs ready

    // ---- involution: thread = 4px strip x 4 channels, mixed-precision FMA ----
    const int strip = t & 31;                // 8 rows x 4 col-groups
    const int chg   = t >> 5;                // 0..7 -> 4 channels each
    const int pr3 = strip >> 2, pc = (strip & 3) * 4;
    const int c0  = chg * 4;

    float acc[4][4];
    #pragma unroll
    for (int i = 0; i < 4; ++i)
        #pragma unroll
        for (int j = 0; j < 4; ++j) acc[i][j] = 0.f;

    #pragma unroll
    for (int kh = 0; kh < 7; ++kh) {
        half4v kcr[7];
        #pragma unroll
        for (int kw = 0; kw < 7; ++kw)
            kcr[kw] = *(const half4v*)&kcS[(kh * 7 + kw) * 128 + pr3 * 16 + pc];
        #pragma unroll
        for (int i = 0; i < 4; ++i) {
            const _Float16* xr = &Xs[(c0 + i) * CSP6 + (pr3 + kh) * RPT6 + pc];
            const half4v xa = *(const half4v*)&xr[0];
            const half4v xb = *(const half4v*)&xr[4];
            const half4v xc = *(const half4v*)&xr[8];
            const _Float16 xw[12] = {xa[0], xa[1], xa[2], xa[3],
                                     xb[0], xb[1], xb[2], xb[3],
                                     xc[0], xc[1], xc[2], xc[3]};
            #pragma unroll
            for (int kw = 0; kw < 7; ++kw)
                #pragma unroll
                for (int j = 0; j < 4; ++j)
                    acc[i][j] = fmaf((float)kcr[kw][j], (float)xw[kw + j], acc[i][j]);
        }
    }

    float* ob = out + (size_t)b * CHW + (size_t)(half * 32 + c0) * HW
                    + (size_t)(th0 + pr3) * W + (tw0 + pc);
    #pragma unroll
    for (int i = 0; i < 4; ++i)
        *(float4*)&ob[(size_t)i * HW] = make_float4(acc[i][0], acc[i][1], acc[i][2], acc[i][3]);
}

// ==================== FALLBACK PATH (round-1, passing) ====================

constexpr int XS_F  = C * 196;
constexpr int KC_F  = KK * 64;
constexpr int ACT_F = Cr * 64;
constexpr int WR_F  = Cr * C;
constexpr int WSP_F = KK * Cr;
constexpr int SMEM_F = XS_F + KC_F + ACT_F + WR_F + WSP_F + KK + Cr + Cr;
constexpr int SMEM_BYTES = SMEM_F * 4;

__global__ __launch_bounds__(128) void k_reduce_stats(
    const float* __restrict__ X, const float* __restrict__ w_reduce,
    const float* __restrict__ b_reduce, float* __restrict__ partial)
{
    __shared__ float wr[WR_F];
    __shared__ float brd[Cr];
    __shared__ float tmp[2][32];
    const int t = threadIdx.x;
    for (int i = t; i < WR_F; i += 128) wr[i] = w_reduce[i];
    if (t < Cr) brd[t] = b_reduce[t];
    __syncthreads();
    const int p  = blockIdx.x * 128 + t;
    const int b  = p >> 14;
    const int hw = p & (HW - 1);
    const float* xb = X + b * CHW + hw;
    float r[Cr];
    #pragma unroll
    for (int o = 0; o < Cr; ++o) r[o] = brd[o];
    #pragma unroll 4
    for (int c = 0; c < C; ++c) {
        const float x = xb[c * HW];
        #pragma unroll
        for (int o = 0; o < Cr; ++o) r[o] = fmaf(x, wr[o * C + c], r[o]);
    }
    const int lane = t & 63, wv = t >> 6;
    #pragma unroll
    for (int o = 0; o < Cr; ++o) {
        float s = r[o], q = r[o] * r[o];
        #pragma unroll
        for (int off = 32; off > 0; off >>= 1) {
            s += __shfl_down(s, off);
            q += __shfl_down(q, off);
        }
        if (lane == 0) { tmp[wv][o] = s; tmp[wv][Cr + o] = q; }
    }
    __syncthreads();
    if (t < 32) partial[blockIdx.x * 32 + t] = tmp[0][t] + tmp[1][t];
}

__global__ __launch_bounds__(256) void k_stats_final(
    const float* __restrict__ partial, float* __restrict__ stats)
{
    __shared__ float red[256];
    __shared__ float fin[32];
    const int t = threadIdx.x;
    const int o = t & 31, g = t >> 5;
    float acc = 0.f;
    #pragma unroll 8
    for (int j = 0; j < 32; ++j) acc += partial[(g * 32 + j) * 32 + o];
    red[t] = acc;
    __syncthreads();
    if (t < 32) {
        float v = 0.f;
        #pragma unroll
        for (int g2 = 0; g2 < 8; ++g2) v += red[g2 * 32 + t];
        fin[t] = v;
    }
    __syncthreads();
    if (t < Cr) {
        const float mean = fin[t] / (float)NPIX;
        const float var  = fin[Cr + t] / (float)NPIX - mean * mean;
        stats[t]      = mean;
        stats[Cr + t] = rsqrtf(var + EPS);
    }
}

__global__ __launch_bounds__(256) void k_involution(
    const float* __restrict__ X, const float* __restrict__ w_reduce,
    const float* __restrict__ b_reduce, const float* __restrict__ gamma,
    const float* __restrict__ beta, const float* __restrict__ w_span,
    const float* __restrict__ b_span, const float* __restrict__ stats,
    float* __restrict__ out)
{
    extern __shared__ float smem[];
    float* Xs   = smem;
    float* kcS  = Xs  + XS_F;
    float* actS = kcS + KC_F;
    float* wrS  = actS + ACT_F;
    float* wspS = wrS + WR_F;
    float* bspS = wspS + WSP_F;
    float* scS  = bspS + KK;
    float* ofS  = scS + Cr;
    const int t    = threadIdx.x;
    const int bx   = blockIdx.x;
    const int b    = bx >> 8;
    const int tile = bx & 255;
    const int h0   = (tile >> 4) << 3;
    const int w0   = (tile & 15) << 3;
    const float* xbg = X + b * CHW;
    for (int idx = t; idx < XS_F; idx += 256) {
        const int c   = idx / 196;
        const int rem = idx - c * 196;
        const int r   = rem / 14;
        const int col = rem - r * 14;
        const int gh  = h0 + r - 3, gw = w0 + col - 3;
        float v = 0.f;
        if ((unsigned)gh < (unsigned)H && (unsigned)gw < (unsigned)W)
            v = xbg[c * HW + gh * W + gw];
        Xs[idx] = v;
    }
    for (int i = t; i < WR_F;  i += 256) wrS[i]  = w_reduce[i];
    for (int i = t; i < WSP_F; i += 256) wspS[i] = w_span[i];
    if (t < KK) bspS[t] = b_span[t];
    if (t < Cr) {
        const float m  = stats[t];
        const float rs = stats[Cr + t];
        const float gm = gamma[t];
        scS[t] = gm * rs;
        ofS[t] = (b_reduce[t] - m) * gm * rs + beta[t];
    }
    __syncthreads();
    const int pix = t & 63;
    const int grp = t >> 6;
    const int ph  = pix >> 3, pw = pix & 7;
    {
        const int base = (ph + 3) * 14 + (pw + 3);
        float d0 = 0.f, d1 = 0.f, d2 = 0.f, d3 = 0.f;
        #pragma unroll 8
        for (int c = 0; c < C; ++c) {
            const float x = Xs[c * 196 + base];
            d0 = fmaf(x, wrS[(grp * 4 + 0) * C + c], d0);
            d1 = fmaf(x, wrS[(grp * 4 + 1) * C + c], d1);
            d2 = fmaf(x, wrS[(grp * 4 + 2) * C + c], d2);
            d3 = fmaf(x, wrS[(grp * 4 + 3) * C + c], d3);
        }
        const float d[4] = {d0, d1, d2, d3};
        #pragma unroll
        for (int j = 0; j < 4; ++j) {
            const int o = grp * 4 + j;
            actS[o * 64 + pix] = fmaxf(fmaf(scS[o], d[j], ofS[o]), 0.f);
        }
    }
    __syncthreads();
    for (int k = grp; k < KK; k += 4) {
        float v = bspS[k];
        #pragma unroll
        for (int o = 0; o < Cr; ++o)
            v = fmaf(actS[o * 64 + pix], wspS[k * Cr + o], v);
        kcS[k * 64 + pix] = v;
    }
    __syncthreads();
    float acc[16];
    #pragma unroll
    for (int i = 0; i < 16; ++i) acc[i] = 0.f;
    const float* xsc = Xs + grp * 16 * 196;
    #pragma unroll
    for (int k = 0; k < KK; ++k) {
        const int kh = k / 7, kw = k - (k / 7) * 7;
        const float kcv = kcS[k * 64 + pix];
        const int xoff = (ph + kh) * 14 + (pw + kw);
        #pragma unroll
        for (int i = 0; i < 16; ++i)
            acc[i] = fmaf(kcv, xsc[i * 196 + xoff], acc[i]);
    }
    float* ob = out + b * CHW + (grp * 16) * HW + (h0 + ph) * W + (w0 + pw);
    #pragma unroll
    for (int i = 0; i < 16; ++i) ob[i * HW] = acc[i];
}

// ==================== launch ====================

extern "C" void kernel_launch(void* const* d_in, const int* in_sizes, int n_in,
                              void* d_out, int out_size, void* d_ws, size_t ws_size,
                              hipStream_t stream) {
    const float* X        = (const float*)d_in[0];
    const float* w_reduce = (const float*)d_in[1];
    const float* b_reduce = (const float*)d_in[2];
    const float* gamma    = (const float*)d_in[3];
    const float* beta     = (const float*)d_in[4];
    const float* w_span   = (const float*)d_in[5];
    const float* b_span   = (const float*)d_in[6];
    float* out = (float*)d_out;
    float* ws  = (float*)d_ws;

    if (ws_size >= WS_NEED) {
        float* r_ws    = ws;
        float* partial = ws + R_F;
        k_reduce_r<<<512, 256, 0, stream>>>(X, w_reduce, b_reduce, r_ws, partial);
        k_inv6<<<512, 256, 0, stream>>>(X, r_ws, partial, gamma, beta,
                                        w_span, b_span, out);
    } else {
        float* partial = ws;
        float* stats   = ws + 8192;
        hipFuncSetAttribute((const void*)k_involution,
                            hipFuncAttributeMaxDynamicSharedMemorySize, SMEM_BYTES);
        k_reduce_stats<<<256, 128, 0, stream>>>(X, w_reduce, b_reduce, partial);
        k_stats_final<<<1, 256, 0, stream>>>(partial, stats);
        k_involution<<<512, 256, SMEM_BYTES, stream>>>(
            X, w_reduce, b_reduce, gamma, beta, w_span, b_span, stats, out);
    }
}